// Round 20
// baseline (483.580 us; speedup 1.0000x reference)
//
#include <hip/hip_runtime.h>
#include <hip/hip_bf16.h>
#include <stddef.h>

// Sizes: N=4, C=64, F=256, T=256, B=N*F=1024, D=128, H=32, 4H=128, NG=384

typedef __bf16 bf16x8 __attribute__((ext_vector_type(8)));
typedef float f32x4 __attribute__((ext_vector_type(4)));

__device__ __forceinline__ ushort f2bf(float x) {   // RTNE
    uint u = __builtin_bit_cast(uint, x);
    uint r = (u + 0x7fffu + ((u >> 16) & 1u)) >> 16;
    return (ushort)r;
}

__device__ __forceinline__ float fsig(float x) {
    return __builtin_amdgcn_rcpf(1.f + __expf(-x));
}
__device__ __forceinline__ float ftanh(float x) {
    return 1.f - 2.f * __builtin_amdgcn_rcpf(__expf(2.f * x) + 1.f);
}
__device__ __forceinline__ float wredsum(float v) {
#pragma unroll
    for (int off = 32; off; off >>= 1) v += __shfl_xor(v, off);
    return v;
}
__device__ __forceinline__ float hredsum(float v) {
#pragma unroll
    for (int off = 16; off; off >>= 1) v += __shfl_xor(v, off);
    return v;
}

// ---------------------------------------------------------------------------
// Kernel 2 (MFMA, fused LN1): gx[M,384](bf16) = LN1(x)[M,128] @ Wcat^T + bias
// Prologue loads the raw input tile (coalesced along t), transposes via LDS
// (xl aliases w_lds), applies LN1 per row, writes bf16 into a_lds.
// Then per l=0..2: stage W, MFMA, permuted epilogue staged in w_lds,
// coalesced uint4 stores. Gate perm: s = 4*j + gi.
// ---------------------------------------------------------------------------
__global__ __launch_bounds__(256) void k_gemm(const float* __restrict__ in,
                                              const float* __restrict__ g1,
                                              const float* __restrict__ b1,
                                              const float* __restrict__ Wq,
                                              const float* __restrict__ Wk,
                                              const float* __restrict__ Wv,
                                              const float* __restrict__ bihq, const float* __restrict__ bhhq,
                                              const float* __restrict__ bihk, const float* __restrict__ bhhk,
                                              const float* __restrict__ bihv, const float* __restrict__ bhhv,
                                              ushort* __restrict__ gx) {
    __shared__ ushort a_lds[128 * 136];
    __shared__ ushort w_lds[128 * 136];
    const int tid = threadIdx.x;
    const int m0 = blockIdx.x * 128;

    const int w = tid >> 6, lane = tid & 63;
    const int wr = w >> 1, wc = w & 1;
    const int row16 = lane & 15, koct = lane >> 4;

    // ---- fused k_prep: LN1 of this block's 128 (b,t) rows into a_lds ----
    {
        const int b_seq = blockIdx.x >> 1;          // 0..1023
        const int t0 = (blockIdx.x & 1) * 128;
        const int n = b_seq >> 8, f = b_seq & 255;
        float (*xl)[129] = (float(*)[129])w_lds;    // alias: w_lds idle here
        const int c = tid >> 2, q = tid & 3;
#pragma unroll 1
        for (int tc = 0; tc < 4; ++tc) {
            const float* src = in + ((size_t)(n * 64 + c) * 256 + f) * 512
                                  + (size_t)(t0 + tc * 32) * 2 + q * 16;
#pragma unroll
            for (int e = 0; e < 4; ++e) {
                float4 v4 = *(const float4*)(src + e * 4);
                int dt = q * 8 + e * 2;
                xl[dt][c]          = v4.x;
                xl[dt][c + 64]     = v4.y;
                xl[dt + 1][c]      = v4.z;
                xl[dt + 1][c + 64] = v4.w;
            }
            __syncthreads();
#pragma unroll 1
            for (int r = 0; r < 8; ++r) {
                int dt = w * 8 + r;
                float a = xl[dt][lane], bb = xl[dt][lane + 64];
                float s = wredsum(a + bb);
                float mean = s * 0.0078125f;
                float da = a - mean, db = bb - mean;
                float var = wredsum(da * da + db * db) * 0.0078125f;
                float inv = __builtin_amdgcn_rsqf(var + 1e-5f);
                int row = tc * 32 + dt;
                a_lds[row * 136 + lane]      = f2bf(da * inv * g1[lane] + b1[lane]);
                a_lds[row * 136 + lane + 64] = f2bf(db * inv * g1[lane + 64] + b1[lane + 64]);
            }
            __syncthreads();
        }
    }

#pragma unroll 1
    for (int l = 0; l < 3; ++l) {
        const float* W   = (l == 0) ? Wq   : (l == 1) ? Wk   : Wv;
        const float* bih = (l == 0) ? bihq : (l == 1) ? bihk : bihv;
        const float* bhh = (l == 0) ? bhhq : (l == 1) ? bhhk : bhhv;
        __syncthreads();   // previous-l stores (from w_lds) done; safe to restage
#pragma unroll
        for (int p = 0; p < 8; ++p) {
            int idx = p * 256 + tid;
            int r = idx >> 4, c = idx & 15;
            const float* wp = W + (size_t)r * 128 + c * 8;
            float4 wa = *(const float4*)wp;
            float4 wb = *(const float4*)(wp + 4);
            union { ushort u[8]; uint4 v; } pk;
            pk.u[0] = f2bf(wa.x); pk.u[1] = f2bf(wa.y); pk.u[2] = f2bf(wa.z); pk.u[3] = f2bf(wa.w);
            pk.u[4] = f2bf(wb.x); pk.u[5] = f2bf(wb.y); pk.u[6] = f2bf(wb.z); pk.u[7] = f2bf(wb.w);
            *(uint4*)&w_lds[r * 136 + c * 8] = pk.v;
        }
        __syncthreads();

        f32x4 acc[4][4];
#pragma unroll
        for (int mi = 0; mi < 4; ++mi)
#pragma unroll
            for (int ni = 0; ni < 4; ++ni) acc[mi][ni] = (f32x4){0.f, 0.f, 0.f, 0.f};

#pragma unroll
        for (int ki = 0; ki < 4; ++ki) {
            bf16x8 af[4], bfr[4];
#pragma unroll
            for (int mi = 0; mi < 4; ++mi)
                af[mi] = *(const bf16x8*)&a_lds[(wr * 64 + mi * 16 + row16) * 136 + ki * 32 + koct * 8];
#pragma unroll
            for (int ni = 0; ni < 4; ++ni)
                bfr[ni] = *(const bf16x8*)&w_lds[(wc * 64 + ni * 16 + row16) * 136 + ki * 32 + koct * 8];
#pragma unroll
            for (int mi = 0; mi < 4; ++mi)
#pragma unroll
                for (int ni = 0; ni < 4; ++ni)
                    acc[mi][ni] = __builtin_amdgcn_mfma_f32_16x16x32_bf16(af[mi], bfr[ni], acc[mi][ni], 0, 0, 0);
        }
        __syncthreads();   // all w_lds MFMA reads complete (all waves)

        // epilogue: bias + s-permuted write into w_lds (scalar, <=2-way banks)
#pragma unroll
        for (int ni = 0; ni < 4; ++ni) {
            int g = wc * 64 + ni * 16 + row16;         // gate 0..127
            float bsv = bih[g] + bhh[g];
            int j = g & 31, gi = g >> 5;
            int s = j * 4 + gi;
#pragma unroll
            for (int mi = 0; mi < 4; ++mi)
#pragma unroll
                for (int q = 0; q < 4; ++q) {
                    int ml = wr * 64 + mi * 16 + koct * 4 + q;
                    w_lds[ml * 136 + s] = f2bf(acc[mi][ni][q] + bsv);
                }
        }
        __syncthreads();
        // coalesced store: 128 rows x 128 ushorts -> full 64B lines
#pragma unroll
        for (int p = 0; p < 8; ++p) {
            int idx = p * 256 + tid;
            int r = idx >> 4, cchunk = idx & 15;
            *(uint4*)&gx[(size_t)(m0 + r) * 384 + l * 128 + cchunk * 8] =
                *(const uint4*)&w_lds[r * 136 + cchunk * 8];
        }
    }
}

// ---------------------------------------------------------------------------
// Kernel 3 (MFMA LSTM, 2-wave gate-split — round-13 version, frozen):
// ---------------------------------------------------------------------------
__global__ __launch_bounds__(128, 1) void k_lstm(const ushort* __restrict__ gx,
                                                 const float* __restrict__ Whq,
                                                 const float* __restrict__ Whk,
                                                 const float* __restrict__ Whv,
                                                 ushort* __restrict__ qkv) {
    __shared__ ushort H[2][16][40];   // [parity][b][j], row stride 80B
    const int tid = threadIdx.x;
    const int w = tid >> 6, lane = tid & 63;
    const int r16 = lane & 15, koct = lane >> 4;
    const int l = blockIdx.x >> 6, bgrp = blockIdx.x & 63;
    const int b = bgrp * 16 + r16;
    const float* Wh = (l == 0) ? Whq : (l == 1) ? Whk : Whv;

    bf16x8 wf[4];
#pragma unroll
    for (int gg = 0; gg < 4; ++gg) {
        int g = 4 * w + gg;
        int jA = 8 * (r16 >> 2) + g;
        int giA = r16 & 3;
        const float* wp = Wh + (size_t)(giA * 32 + jA) * 32 + koct * 8;
        float4 wa = *(const float4*)wp;
        float4 wb = *(const float4*)(wp + 4);
        union { ushort u[8]; bf16x8 v; } pk;
        pk.u[0] = f2bf(wa.x); pk.u[1] = f2bf(wa.y); pk.u[2] = f2bf(wa.z); pk.u[3] = f2bf(wa.w);
        pk.u[4] = f2bf(wb.x); pk.u[5] = f2bf(wb.y); pk.u[6] = f2bf(wb.z); pk.u[7] = f2bf(wb.w);
        wf[gg] = pk.v;
    }

    const ushort* gp = gx + (size_t)b * 98304 + l * 128 + koct * 32 + w * 16;
    uint4 pf[4][2];
#pragma unroll
    for (int tt = 0; tt < 4; ++tt) {
        pf[tt][0] = *(const uint4*)(gp + (size_t)tt * 384);
        pf[tt][1] = *(const uint4*)(gp + (size_t)tt * 384 + 8);
    }

    for (int i = tid; i < 320; i += 128) ((uint*)&H[0][0][0])[i] = 0;
    __syncthreads();

    float cst[4] = {0.f, 0.f, 0.f, 0.f};
    ushort* outp = qkv + ((size_t)(l * 1024 + b)) * 8192 + koct * 8 + w * 4;

#pragma unroll 4
    for (int t = 0; t < 256; ++t) {
        const int sl = t & 3;
        const int p = t & 1;
        bf16x8 hf = *(const bf16x8*)&H[p][r16][koct * 8];

        uint u[8];
        u[0] = pf[sl][0].x; u[1] = pf[sl][0].y; u[2] = pf[sl][0].z; u[3] = pf[sl][0].w;
        u[4] = pf[sl][1].x; u[5] = pf[sl][1].y; u[6] = pf[sl][1].z; u[7] = pf[sl][1].w;
        pf[sl][0] = *(const uint4*)(gp + (size_t)(t + 4) * 384);
        pf[sl][1] = *(const uint4*)(gp + (size_t)(t + 4) * 384 + 8);

        f32x4 acc[4];
#pragma unroll
        for (int gg = 0; gg < 4; ++gg)
#pragma unroll
            for (int q = 0; q < 4; ++q) {
                int v = gg * 4 + q;
                uint w32 = u[v >> 1];
                acc[gg][q] = __builtin_bit_cast(float, (v & 1) ? (w32 & 0xffff0000u) : (w32 << 16));
            }
#pragma unroll
        for (int gg = 0; gg < 4; ++gg)
            acc[gg] = __builtin_amdgcn_mfma_f32_16x16x32_bf16(wf[gg], hf, acc[gg], 0, 0, 0);

        float hv[4];
#pragma unroll
        for (int gg = 0; gg < 4; ++gg) {
            float gi = acc[gg][0], gf = acc[gg][1], gg2 = acc[gg][2], go = acc[gg][3];
            float cN = fsig(gf) * cst[gg] + fsig(gi) * ftanh(gg2);
            cst[gg] = cN;
            hv[gg] = fsig(go) * ftanh(cN);
        }
        uint2 hp;
        __asm__ volatile("v_cvt_pk_bf16_f32 %0, %1, %2" : "=v"(hp.x) : "v"(hv[0]), "v"(hv[1]));
        __asm__ volatile("v_cvt_pk_bf16_f32 %0, %1, %2" : "=v"(hp.y) : "v"(hv[2]), "v"(hv[3]));
        *(uint2*)&H[p ^ 1][r16][koct * 8 + w * 4] = hp;
        *(uint2*)(outp + (size_t)t * 32) = hp;
        __syncthreads();
    }
}

// ---------------------------------------------------------------------------
// Kernel 4 (MFMA): attention. 1 block per b, 4 waves x 64 q-rows each.
// ---------------------------------------------------------------------------
__global__ __launch_bounds__(256) void k_attn(const ushort* __restrict__ qkvb,
                                              float* __restrict__ wvout) {
    __shared__ ushort k_sw[256 * 32];      // 16 KiB
    __shared__ ushort vt_sw[32 * 256];     // 16 KiB
    __shared__ ushort p_sw[4][16 * 256];   // 32 KiB (per-wave private)
    const int tid = threadIdx.x, w = tid >> 6, lane = tid & 63;
    const int b = blockIdx.x;
    const ushort* qb = qkvb + (size_t)b * 8192;
    const ushort* kb = qkvb + 8388608 + (size_t)b * 8192;
    const ushort* vb = qkvb + 16777216 + (size_t)b * 8192;
#pragma unroll
    for (int p = 0; p < 4; ++p) {
        int idx = p * 256 + tid;           // 0..1023 chunks of 8 bf16
        int s = idx >> 2, cc = idx & 3;
        uint4 kv = *(const uint4*)(kb + s * 32 + cc * 8);
        int cK = cc ^ ((s >> 1) & 3);
        *(uint4*)&k_sw[s * 32 + cK * 8] = kv;
        uint4 vv = *(const uint4*)(vb + s * 32 + cc * 8);
        union { uint4 v; ushort u[8]; } un; un.v = vv;
#pragma unroll
        for (int e = 0; e < 8; ++e) {
            int row = cc * 8 + e;
            vt_sw[row * 256 + (((s >> 3) ^ (row & 7)) << 3) + (s & 7)] = un.u[e];
        }
    }
    __syncthreads();
    const int r16 = lane & 15, koct = lane >> 4;
    ushort* pw = p_sw[w];
    bf16x8 qf[4];
#pragma unroll
    for (int i = 0; i < 4; ++i) {
        int t = (w * 4 + i) * 16 + r16;
        qf[i] = *(const bf16x8*)(qb + t * 32 + koct * 8);
    }
#pragma unroll 1
    for (int i = 0; i < 4; ++i) {
        const int tb = (w * 4 + i) * 16;
        f32x4 acc[16];
#pragma unroll
        for (int st = 0; st < 16; ++st) acc[st] = (f32x4){0.f, 0.f, 0.f, 0.f};
#pragma unroll
        for (int st = 0; st < 16; ++st) {
            int s = st * 16 + r16;
            int cK = koct ^ ((s >> 1) & 3);
            bf16x8 kf = *(const bf16x8*)&k_sw[s * 32 + cK * 8];
            acc[st] = __builtin_amdgcn_mfma_f32_16x16x32_bf16(qf[i], kf, acc[st], 0, 0, 0);
        }
        float mx[4] = {-1e30f, -1e30f, -1e30f, -1e30f};
#pragma unroll
        for (int st = 0; st < 16; ++st) {
            int s = st * 16 + r16;
#pragma unroll
            for (int q = 0; q < 4; ++q) {
                int t = tb + koct * 4 + q;
                float v = (s <= t) ? acc[st][q] * 0.25f : 0.f;
                acc[st][q] = v;
                mx[q] = fmaxf(mx[q], v);
            }
        }
#pragma unroll
        for (int off = 1; off < 16; off <<= 1)
#pragma unroll
            for (int q = 0; q < 4; ++q) mx[q] = fmaxf(mx[q], __shfl_xor(mx[q], off));
        float sm[4] = {0.f, 0.f, 0.f, 0.f};
#pragma unroll
        for (int st = 0; st < 16; ++st)
#pragma unroll
            for (int q = 0; q < 4; ++q) {
                float p = __expf(acc[st][q] - mx[q]);
                acc[st][q] = p; sm[q] += p;
            }
#pragma unroll
        for (int off = 1; off < 16; off <<= 1)
#pragma unroll
            for (int q = 0; q < 4; ++q) sm[q] += __shfl_xor(sm[q], off);
        float rs[4];
#pragma unroll
        for (int q = 0; q < 4; ++q) rs[q] = __builtin_amdgcn_rcpf(sm[q]);
#pragma unroll
        for (int st = 0; st < 16; ++st) {
            int schunk = st * 2 + (r16 >> 3), sl = r16 & 7;
#pragma unroll
            for (int q = 0; q < 4; ++q) {
                int tl = koct * 4 + q;
                pw[tl * 256 + ((schunk ^ (tl & 7)) << 3) + sl] = f2bf(acc[st][q] * rs[q]);
            }
        }
        __asm__ volatile("s_waitcnt lgkmcnt(0)" ::: "memory");
        f32x4 oa[2];
        oa[0] = (f32x4){0.f, 0.f, 0.f, 0.f};
        oa[1] = (f32x4){0.f, 0.f, 0.f, 0.f};
#pragma unroll
        for (int ks = 0; ks < 8; ++ks) {
            int kc = ks * 4 + koct;
            bf16x8 pa = *(const bf16x8*)&pw[r16 * 256 + ((kc ^ (r16 & 7)) << 3)];
#pragma unroll
            for (int n = 0; n < 2; ++n) {
                int row = n * 16 + r16;
                bf16x8 vf = *(const bf16x8*)&vt_sw[row * 256 + ((kc ^ (row & 7)) << 3)];
                oa[n] = __builtin_amdgcn_mfma_f32_16x16x32_bf16(pa, vf, oa[n], 0, 0, 0);
            }
        }
#pragma unroll
        for (int n = 0; n < 2; ++n)
#pragma unroll
            for (int q = 0; q < 4; ++q)
                wvout[((size_t)b * 256 + tb + koct * 4 + q) * 32 + n * 16 + r16] = oa[n][q];
    }
}

// ---------------------------------------------------------------------------
// Kernel 5 (round-13): LN2 + complex linear via MFMA (K=32) + one-pass LN3
// + PReLU + residual.
// ---------------------------------------------------------------------------
__global__ __launch_bounds__(256) void k_post(const float* __restrict__ wv,
                                              const float* __restrict__ in,
                                              const float* __restrict__ g2,
                                              const float* __restrict__ b2,
                                              const float* __restrict__ Wr,
                                              const float* __restrict__ br,
                                              const float* __restrict__ Wi,
                                              const float* __restrict__ bi,
                                              const float* __restrict__ g3,
                                              const float* __restrict__ b3,
                                              const float* __restrict__ pa,
                                              float* __restrict__ outp) {
    __shared__ float xv[32][36];          // 144B row stride
    __shared__ float out_s[64][65];
    const int tid = threadIdx.x;
    const int n = blockIdx.z, f = blockIdx.y, t0 = blockIdx.x * 32;
    const int b = n * 256 + f;
    const int lane = tid & 63, w = tid >> 6;
    const int r16 = lane & 15, koct = lane >> 4;
    const int tt = w & 1, ri = w >> 1;

    for (int idx = tid; idx < 1024; idx += 256) {
        int dt = idx >> 5, j = idx & 31;
        xv[dt][j] = wv[((size_t)b * 256 + t0 + dt) * 32 + j];
    }

    bf16x8 bfr[4];
    float bias_v[4], g3v[4], b3v[4];
    const int kofs = (koct < 2) ? koct * 8 : (koct - 2) * 8;
#pragma unroll
    for (int ct = 0; ct < 4; ++ct) {
        int c = ct * 16 + r16;
        const float* srcW = (ri == 0) ? ((koct < 2) ? Wr : Wi)
                                      : ((koct < 2) ? Wi : Wr);
        float sgn = (ri == 0 && koct >= 2) ? -1.f : 1.f;
        float4 wa = *(const float4*)(srcW + c * 16 + kofs);
        float4 wb = *(const float4*)(srcW + c * 16 + kofs + 4);
        union { ushort u[8]; bf16x8 v; } pk;
        pk.u[0] = f2bf(sgn * wa.x); pk.u[1] = f2bf(sgn * wa.y);
        pk.u[2] = f2bf(sgn * wa.z); pk.u[3] = f2bf(sgn * wa.w);
        pk.u[4] = f2bf(sgn * wb.x); pk.u[5] = f2bf(sgn * wb.y);
        pk.u[6] = f2bf(sgn * wb.z); pk.u[7] = f2bf(sgn * wb.w);
        bfr[ct] = pk.v;
        bias_v[ct] = (ri == 0) ? (br[c] - bi[c]) : (br[c] + bi[c]);
        g3v[ct] = g3[c];
        b3v[ct] = b3[c];
    }
    const float alpha = pa[0];
    __syncthreads();

#pragma unroll 1
    for (int r = 0; r < 4; ++r) {
        int dt = w * 8 + r * 2 + (lane >> 5);
        int j = lane & 31;
        float v = xv[dt][j];
        float mean = hredsum(v) * 0.03125f;
        float d = v - mean;
        float var = hredsum(d * d) * 0.03125f;
        float inv = __builtin_amdgcn_rsqf(var + 1e-5f);
        xv[dt][j] = d * inv * g2[j] + b2[j];
    }
    __syncthreads();

    const float* xrow = &xv[tt * 16 + r16][koct * 8];
    float4 a0 = *(const float4*)xrow;
    float4 a1 = *(const float4*)(xrow + 4);
    uint4 ap;
    __asm__ volatile("v_cvt_pk_bf16_f32 %0, %1, %2" : "=v"(ap.x) : "v"(a0.x), "v"(a0.y));
    __asm__ volatile("v_cvt_pk_bf16_f32 %0, %1, %2" : "=v"(ap.y) : "v"(a0.z), "v"(a0.w));
    __asm__ volatile("v_cvt_pk_bf16_f32 %0, %1, %2" : "=v"(ap.z) : "v"(a1.x), "v"(a1.y));
    __asm__ volatile("v_cvt_pk_bf16_f32 %0, %1, %2" : "=v"(ap.w) : "v"(a1.z), "v"(a1.w));
    bf16x8 af = __builtin_bit_cast(bf16x8, ap);

    f32x4 acc[4];
#pragma unroll
    for (int ct = 0; ct < 4; ++ct) {
        acc[ct] = (f32x4){0.f, 0.f, 0.f, 0.f};
        acc[ct] = __builtin_amdgcn_mfma_f32_16x16x32_bf16(af, bfr[ct], acc[ct], 0, 0, 0);
    }

    float val[4][4];
    float s[4] = {0.f, 0.f, 0.f, 0.f}, sq[4] = {0.f, 0.f, 0.f, 0.f};
#pragma unroll
    for (int ct = 0; ct < 4; ++ct)
#pragma unroll
        for (int q = 0; q < 4; ++q) {
            float v = acc[ct][q] + bias_v[ct];
            val[ct][q] = v;
            s[q] += v;
            sq[q] += v * v;
        }
#pragma unroll
    for (int off = 1; off < 16; off <<= 1)
#pragma unroll
        for (int q = 0; q < 4; ++q) {
            s[q]  += __shfl_xor(s[q], off);
            sq[q] += __shfl_xor(sq[q], off);
        }
#pragma unroll
    for (int q = 0; q < 4; ++q) {
        float m = s[q] * 0.015625f;
        float var = fmaxf(sq[q] * 0.015625f - m * m, 0.f);
        float inv = __builtin_amdgcn_rsqf(var + 1e-5f);
        int t2 = (tt * 16 + koct * 4 + q) * 2 + ri;
#pragma unroll
        for (int ct = 0; ct < 4; ++ct) {
            float nv = (val[ct][q] - m) * inv * g3v[ct] + b3v[ct];
            nv = (nv >= 0.f) ? nv : alpha * nv;
            out_s[ct * 16 + r16][t2] = nv;
        }
    }
    __syncthreads();

    const int cc = tid >> 2, q = tid & 3;
    size_t base = ((size_t)(n * 64 + cc) * 256 + f) * 512 + t0 * 2 + q * 16;
#pragma unroll
    for (int e = 0; e < 4; ++e) {
        float4 iv = *(const float4*)(in + base + e * 4);
        int k0 = q * 16 + e * 4;
        float4 ov;
        ov.x = out_s[cc][k0]     + iv.x;
        ov.y = out_s[cc][k0 + 1] + iv.y;
        ov.z = out_s[cc][k0 + 2] + iv.z;
        ov.w = out_s[cc][k0 + 3] + iv.w;
        *(float4*)(outp + base + e * 4) = ov;
    }
}

// ---------------------------------------------------------------------------
extern "C" void kernel_launch(void* const* d_in, const int* in_sizes, int n_in,
                              void* d_out, int out_size, void* d_ws, size_t ws_size,
                              hipStream_t stream) {
    const float* in   = (const float*)d_in[0];
    const float* g1   = (const float*)d_in[1];
    const float* b1   = (const float*)d_in[2];
    const float* Wq   = (const float*)d_in[3];
    const float* Whq  = (const float*)d_in[4];
    const float* bihq = (const float*)d_in[5];
    const float* bhhq = (const float*)d_in[6];
    const float* Wk   = (const float*)d_in[7];
    const float* Whk  = (const float*)d_in[8];
    const float* bihk = (const float*)d_in[9];
    const float* bhhk = (const float*)d_in[10];
    const float* Wv   = (const float*)d_in[11];
    const float* Whv  = (const float*)d_in[12];
    const float* bihv = (const float*)d_in[13];
    const float* bhhv = (const float*)d_in[14];
    const float* g2   = (const float*)d_in[15];
    const float* b2   = (const float*)d_in[16];
    const float* Wr   = (const float*)d_in[17];
    const float* br   = (const float*)d_in[18];
    const float* Wi   = (const float*)d_in[19];
    const float* bi   = (const float*)d_in[20];
    const float* g3   = (const float*)d_in[21];
    const float* b3   = (const float*)d_in[22];
    const float* pa   = (const float*)d_in[23];
    float* outp = (float*)d_out;

    // workspace layout (bytes):
    // [0, 201326592)            gx  bf16  262144*384*2
    // [268435456, 318767104)    qkv bf16  3*262144*32*2
    // [318767104, 352321536)    wv  fp32  262144*32*4
    ushort* gxb  = (ushort*)d_ws;
    ushort* qkvb = (ushort*)((char*)d_ws + 268435456);
    float*  wvb  = (float*)((char*)d_ws + 318767104);

    k_gemm<<<dim3(2048), dim3(256), 0, stream>>>(in, g1, b1, Wq, Wk, Wv,
                                                 bihq, bhhq, bihk, bhhk, bihv, bhhv, gxb);
    k_lstm<<<dim3(192), dim3(128), 0, stream>>>(gxb, Whq, Whk, Whv, qkvb);
    k_attn<<<dim3(1024), dim3(256), 0, stream>>>(qkvb, wvb);
    k_post<<<dim3(8, 256, 4), dim3(256), 0, stream>>>(wvb, in, g2, b2,
                                                      Wr, br, Wi, bi, g3, b3, pa, outp);
}

// Round 21
// 472.430 us; speedup vs baseline: 1.0236x; 1.0236x over previous
//
#include <hip/hip_runtime.h>
#include <hip/hip_bf16.h>
#include <stddef.h>

// Sizes: N=4, C=64, F=256, T=256, B=N*F=1024, D=128, H=32, 4H=128, NG=384

typedef __bf16 bf16x8 __attribute__((ext_vector_type(8)));
typedef float f32x4 __attribute__((ext_vector_type(4)));

__device__ __forceinline__ ushort f2bf(float x) {   // RTNE
    uint u = __builtin_bit_cast(uint, x);
    uint r = (u + 0x7fffu + ((u >> 16) & 1u)) >> 16;
    return (ushort)r;
}

__device__ __forceinline__ float fsig(float x) {
    return __builtin_amdgcn_rcpf(1.f + __expf(-x));
}
__device__ __forceinline__ float ftanh(float x) {
    return 1.f - 2.f * __builtin_amdgcn_rcpf(__expf(2.f * x) + 1.f);
}
__device__ __forceinline__ float wredsum(float v) {
#pragma unroll
    for (int off = 32; off; off >>= 1) v += __shfl_xor(v, off);
    return v;
}
__device__ __forceinline__ float hredsum(float v) {
#pragma unroll
    for (int off = 16; off; off >>= 1) v += __shfl_xor(v, off);
    return v;
}

// ---------------------------------------------------------------------------
// Kernel 1: inputs [N,C,F,T,2] -> xn [B,T,128] (bf16) with LN1 fused.
// Round-21: one-pass LN (sum & sumsq chains interleaved).
// ---------------------------------------------------------------------------
__global__ __launch_bounds__(256) void k_prep(const float* __restrict__ in,
                                              const float* __restrict__ g1,
                                              const float* __restrict__ b1,
                                              ushort* __restrict__ xn) {
    __shared__ float xl[32][129];
    const int n = blockIdx.z, f = blockIdx.y, t0 = blockIdx.x * 32;
    const int tid = threadIdx.x;
    const int c = tid >> 2, q = tid & 3;
    const float* src = in + ((size_t)(n * 64 + c) * 256 + f) * 512 + t0 * 2 + q * 16;
#pragma unroll
    for (int e = 0; e < 4; ++e) {
        float4 v4 = *(const float4*)(src + e * 4);
        int dt = q * 8 + e * 2;
        xl[dt][c]          = v4.x;
        xl[dt][c + 64]     = v4.y;
        xl[dt + 1][c]      = v4.z;
        xl[dt + 1][c + 64] = v4.w;
    }
    __syncthreads();
    const int lane = tid & 63, w = tid >> 6;
    const int b = n * 256 + f;
#pragma unroll 1
    for (int r = 0; r < 8; ++r) {
        int dt = w * 8 + r;
        float a = xl[dt][lane], bb = xl[dt][lane + 64];
        float s = a + bb, sq = a * a + bb * bb;
#pragma unroll
        for (int off = 32; off; off >>= 1) {
            s  += __shfl_xor(s, off);
            sq += __shfl_xor(sq, off);
        }
        float mean = s * 0.0078125f;               // /128
        float var = fmaxf(sq * 0.0078125f - mean * mean, 0.f);
        float inv = __builtin_amdgcn_rsqf(var + 1e-5f);
        size_t base = ((size_t)b * 256 + (t0 + dt)) * 128;
        xn[base + lane]      = f2bf((a - mean) * inv * g1[lane] + b1[lane]);
        xn[base + lane + 64] = f2bf((bb - mean) * inv * g1[lane + 64] + b1[lane + 64]);
    }
}

// ---------------------------------------------------------------------------
// Kernel 2 (MFMA): gx[M,384](bf16) = xn[M,128](bf16) @ Wcat^T + (bih+bhh)
// One block per 128-row m-tile; loops l=0..2 (A staged once, W restaged).
// Gate storage permuted: s = 4*j + gi (j=g&31, gi=g>>5).
// Epilogue staged in w_lds -> coalesced uint4 stores (round-19).
// ---------------------------------------------------------------------------
__global__ __launch_bounds__(256) void k_gemm(const ushort* __restrict__ xn,
                                              const float* __restrict__ Wq,
                                              const float* __restrict__ Wk,
                                              const float* __restrict__ Wv,
                                              const float* __restrict__ bihq, const float* __restrict__ bhhq,
                                              const float* __restrict__ bihk, const float* __restrict__ bhhk,
                                              const float* __restrict__ bihv, const float* __restrict__ bhhv,
                                              ushort* __restrict__ gx) {
    __shared__ ushort a_lds[128 * 136];
    __shared__ ushort w_lds[128 * 136];
    const int tid = threadIdx.x;
    const int m0 = blockIdx.x * 128;

#pragma unroll
    for (int p = 0; p < 8; ++p) {
        int idx = p * 256 + tid;
        int r = idx >> 4, c = idx & 15;
        *(uint4*)&a_lds[r * 136 + c * 8] =
            *(const uint4*)(xn + (size_t)(m0 + r) * 128 + c * 8);
    }

    const int w = tid >> 6, lane = tid & 63;
    const int wr = w >> 1, wc = w & 1;
    const int row16 = lane & 15, koct = lane >> 4;

#pragma unroll 1
    for (int l = 0; l < 3; ++l) {
        const float* W   = (l == 0) ? Wq   : (l == 1) ? Wk   : Wv;
        const float* bih = (l == 0) ? bihq : (l == 1) ? bihk : bihv;
        const float* bhh = (l == 0) ? bhhq : (l == 1) ? bhhk : bhhv;
        __syncthreads();   // previous-l stores (from w_lds) done; safe to restage
#pragma unroll
        for (int p = 0; p < 8; ++p) {
            int idx = p * 256 + tid;
            int r = idx >> 4, c = idx & 15;
            const float* wp = W + (size_t)r * 128 + c * 8;
            float4 wa = *(const float4*)wp;
            float4 wb = *(const float4*)(wp + 4);
            union { ushort u[8]; uint4 v; } pk;
            pk.u[0] = f2bf(wa.x); pk.u[1] = f2bf(wa.y); pk.u[2] = f2bf(wa.z); pk.u[3] = f2bf(wa.w);
            pk.u[4] = f2bf(wb.x); pk.u[5] = f2bf(wb.y); pk.u[6] = f2bf(wb.z); pk.u[7] = f2bf(wb.w);
            *(uint4*)&w_lds[r * 136 + c * 8] = pk.v;
        }
        __syncthreads();

        f32x4 acc[4][4];
#pragma unroll
        for (int mi = 0; mi < 4; ++mi)
#pragma unroll
            for (int ni = 0; ni < 4; ++ni) acc[mi][ni] = (f32x4){0.f, 0.f, 0.f, 0.f};

#pragma unroll
        for (int ki = 0; ki < 4; ++ki) {
            bf16x8 af[4], bfr[4];
#pragma unroll
            for (int mi = 0; mi < 4; ++mi)
                af[mi] = *(const bf16x8*)&a_lds[(wr * 64 + mi * 16 + row16) * 136 + ki * 32 + koct * 8];
#pragma unroll
            for (int ni = 0; ni < 4; ++ni)
                bfr[ni] = *(const bf16x8*)&w_lds[(wc * 64 + ni * 16 + row16) * 136 + ki * 32 + koct * 8];
#pragma unroll
            for (int mi = 0; mi < 4; ++mi)
#pragma unroll
                for (int ni = 0; ni < 4; ++ni)
                    acc[mi][ni] = __builtin_amdgcn_mfma_f32_16x16x32_bf16(af[mi], bfr[ni], acc[mi][ni], 0, 0, 0);
        }
        __syncthreads();   // all w_lds MFMA reads complete (all waves)

        // epilogue: bias + s-permuted write into w_lds (scalar, <=2-way banks)
#pragma unroll
        for (int ni = 0; ni < 4; ++ni) {
            int g = wc * 64 + ni * 16 + row16;         // gate 0..127
            float bsv = bih[g] + bhh[g];
            int j = g & 31, gi = g >> 5;
            int s = j * 4 + gi;
#pragma unroll
            for (int mi = 0; mi < 4; ++mi)
#pragma unroll
                for (int q = 0; q < 4; ++q) {
                    int ml = wr * 64 + mi * 16 + koct * 4 + q;
                    w_lds[ml * 136 + s] = f2bf(acc[mi][ni][q] + bsv);
                }
        }
        __syncthreads();
        // coalesced store: 128 rows x 128 ushorts -> full 64B lines
#pragma unroll
        for (int p = 0; p < 8; ++p) {
            int idx = p * 256 + tid;
            int r = idx >> 4, cchunk = idx & 15;
            *(uint4*)&gx[(size_t)(m0 + r) * 384 + l * 128 + cchunk * 8] =
                *(const uint4*)&w_lds[r * 136 + cchunk * 8];
        }
    }
}

// ---------------------------------------------------------------------------
// Kernel 3 (MFMA LSTM, 2-wave gate-split — round-13 version, frozen):
// ---------------------------------------------------------------------------
__global__ __launch_bounds__(128, 1) void k_lstm(const ushort* __restrict__ gx,
                                                 const float* __restrict__ Whq,
                                                 const float* __restrict__ Whk,
                                                 const float* __restrict__ Whv,
                                                 ushort* __restrict__ qkv) {
    __shared__ ushort H[2][16][40];   // [parity][b][j], row stride 80B
    const int tid = threadIdx.x;
    const int w = tid >> 6, lane = tid & 63;
    const int r16 = lane & 15, koct = lane >> 4;
    const int l = blockIdx.x >> 6, bgrp = blockIdx.x & 63;
    const int b = bgrp * 16 + r16;
    const float* Wh = (l == 0) ? Whq : (l == 1) ? Whk : Whv;

    bf16x8 wf[4];
#pragma unroll
    for (int gg = 0; gg < 4; ++gg) {
        int g = 4 * w + gg;
        int jA = 8 * (r16 >> 2) + g;
        int giA = r16 & 3;
        const float* wp = Wh + (size_t)(giA * 32 + jA) * 32 + koct * 8;
        float4 wa = *(const float4*)wp;
        float4 wb = *(const float4*)(wp + 4);
        union { ushort u[8]; bf16x8 v; } pk;
        pk.u[0] = f2bf(wa.x); pk.u[1] = f2bf(wa.y); pk.u[2] = f2bf(wa.z); pk.u[3] = f2bf(wa.w);
        pk.u[4] = f2bf(wb.x); pk.u[5] = f2bf(wb.y); pk.u[6] = f2bf(wb.z); pk.u[7] = f2bf(wb.w);
        wf[gg] = pk.v;
    }

    const ushort* gp = gx + (size_t)b * 98304 + l * 128 + koct * 32 + w * 16;
    uint4 pf[4][2];
#pragma unroll
    for (int tt = 0; tt < 4; ++tt) {
        pf[tt][0] = *(const uint4*)(gp + (size_t)tt * 384);
        pf[tt][1] = *(const uint4*)(gp + (size_t)tt * 384 + 8);
    }

    for (int i = tid; i < 320; i += 128) ((uint*)&H[0][0][0])[i] = 0;
    __syncthreads();

    float cst[4] = {0.f, 0.f, 0.f, 0.f};
    ushort* outp = qkv + ((size_t)(l * 1024 + b)) * 8192 + koct * 8 + w * 4;

#pragma unroll 4
    for (int t = 0; t < 256; ++t) {
        const int sl = t & 3;
        const int p = t & 1;
        bf16x8 hf = *(const bf16x8*)&H[p][r16][koct * 8];

        uint u[8];
        u[0] = pf[sl][0].x; u[1] = pf[sl][0].y; u[2] = pf[sl][0].z; u[3] = pf[sl][0].w;
        u[4] = pf[sl][1].x; u[5] = pf[sl][1].y; u[6] = pf[sl][1].z; u[7] = pf[sl][1].w;
        pf[sl][0] = *(const uint4*)(gp + (size_t)(t + 4) * 384);
        pf[sl][1] = *(const uint4*)(gp + (size_t)(t + 4) * 384 + 8);

        f32x4 acc[4];
#pragma unroll
        for (int gg = 0; gg < 4; ++gg)
#pragma unroll
            for (int q = 0; q < 4; ++q) {
                int v = gg * 4 + q;
                uint w32 = u[v >> 1];
                acc[gg][q] = __builtin_bit_cast(float, (v & 1) ? (w32 & 0xffff0000u) : (w32 << 16));
            }
#pragma unroll
        for (int gg = 0; gg < 4; ++gg)
            acc[gg] = __builtin_amdgcn_mfma_f32_16x16x32_bf16(wf[gg], hf, acc[gg], 0, 0, 0);

        float hv[4];
#pragma unroll
        for (int gg = 0; gg < 4; ++gg) {
            float gi = acc[gg][0], gf = acc[gg][1], gg2 = acc[gg][2], go = acc[gg][3];
            float cN = fsig(gf) * cst[gg] + fsig(gi) * ftanh(gg2);
            cst[gg] = cN;
            hv[gg] = fsig(go) * ftanh(cN);
        }
        uint2 hp;
        __asm__ volatile("v_cvt_pk_bf16_f32 %0, %1, %2" : "=v"(hp.x) : "v"(hv[0]), "v"(hv[1]));
        __asm__ volatile("v_cvt_pk_bf16_f32 %0, %1, %2" : "=v"(hp.y) : "v"(hv[2]), "v"(hv[3]));
        *(uint2*)&H[p ^ 1][r16][koct * 8 + w * 4] = hp;
        *(uint2*)(outp + (size_t)t * 32) = hp;
        __syncthreads();
    }
}

// ---------------------------------------------------------------------------
// Kernel 4 (MFMA): attention. 1 block per b, 4 waves x 64 q-rows each.
// ---------------------------------------------------------------------------
__global__ __launch_bounds__(256) void k_attn(const ushort* __restrict__ qkvb,
                                              float* __restrict__ wvout) {
    __shared__ ushort k_sw[256 * 32];      // 16 KiB
    __shared__ ushort vt_sw[32 * 256];     // 16 KiB
    __shared__ ushort p_sw[4][16 * 256];   // 32 KiB (per-wave private)
    const int tid = threadIdx.x, w = tid >> 6, lane = tid & 63;
    const int b = blockIdx.x;
    const ushort* qb = qkvb + (size_t)b * 8192;
    const ushort* kb = qkvb + 8388608 + (size_t)b * 8192;
    const ushort* vb = qkvb + 16777216 + (size_t)b * 8192;
#pragma unroll
    for (int p = 0; p < 4; ++p) {
        int idx = p * 256 + tid;           // 0..1023 chunks of 8 bf16
        int s = idx >> 2, cc = idx & 3;
        uint4 kv = *(const uint4*)(kb + s * 32 + cc * 8);
        int cK = cc ^ ((s >> 1) & 3);
        *(uint4*)&k_sw[s * 32 + cK * 8] = kv;
        uint4 vv = *(const uint4*)(vb + s * 32 + cc * 8);
        union { uint4 v; ushort u[8]; } un; un.v = vv;
#pragma unroll
        for (int e = 0; e < 8; ++e) {
            int row = cc * 8 + e;
            vt_sw[row * 256 + (((s >> 3) ^ (row & 7)) << 3) + (s & 7)] = un.u[e];
        }
    }
    __syncthreads();
    const int r16 = lane & 15, koct = lane >> 4;
    ushort* pw = p_sw[w];
    bf16x8 qf[4];
#pragma unroll
    for (int i = 0; i < 4; ++i) {
        int t = (w * 4 + i) * 16 + r16;
        qf[i] = *(const bf16x8*)(qb + t * 32 + koct * 8);
    }
#pragma unroll 1
    for (int i = 0; i < 4; ++i) {
        const int tb = (w * 4 + i) * 16;
        f32x4 acc[16];
#pragma unroll
        for (int st = 0; st < 16; ++st) acc[st] = (f32x4){0.f, 0.f, 0.f, 0.f};
#pragma unroll
        for (int st = 0; st < 16; ++st) {
            int s = st * 16 + r16;
            int cK = koct ^ ((s >> 1) & 3);
            bf16x8 kf = *(const bf16x8*)&k_sw[s * 32 + cK * 8];
            acc[st] = __builtin_amdgcn_mfma_f32_16x16x32_bf16(qf[i], kf, acc[st], 0, 0, 0);
        }
        float mx[4] = {-1e30f, -1e30f, -1e30f, -1e30f};
#pragma unroll
        for (int st = 0; st < 16; ++st) {
            int s = st * 16 + r16;
#pragma unroll
            for (int q = 0; q < 4; ++q) {
                int t = tb + koct * 4 + q;
                float v = (s <= t) ? acc[st][q] * 0.25f : 0.f;
                acc[st][q] = v;
                mx[q] = fmaxf(mx[q], v);
            }
        }
#pragma unroll
        for (int off = 1; off < 16; off <<= 1)
#pragma unroll
            for (int q = 0; q < 4; ++q) mx[q] = fmaxf(mx[q], __shfl_xor(mx[q], off));
        float sm[4] = {0.f, 0.f, 0.f, 0.f};
#pragma unroll
        for (int st = 0; st < 16; ++st)
#pragma unroll
            for (int q = 0; q < 4; ++q) {
                float p = __expf(acc[st][q] - mx[q]);
                acc[st][q] = p; sm[q] += p;
            }
#pragma unroll
        for (int off = 1; off < 16; off <<= 1)
#pragma unroll
            for (int q = 0; q < 4; ++q) sm[q] += __shfl_xor(sm[q], off);
        float rs[4];
#pragma unroll
        for (int q = 0; q < 4; ++q) rs[q] = __builtin_amdgcn_rcpf(sm[q]);
#pragma unroll
        for (int st = 0; st < 16; ++st) {
            int schunk = st * 2 + (r16 >> 3), sl = r16 & 7;
#pragma unroll
            for (int q = 0; q < 4; ++q) {
                int tl = koct * 4 + q;
                pw[tl * 256 + ((schunk ^ (tl & 7)) << 3) + sl] = f2bf(acc[st][q] * rs[q]);
            }
        }
        __asm__ volatile("s_waitcnt lgkmcnt(0)" ::: "memory");
        f32x4 oa[2];
        oa[0] = (f32x4){0.f, 0.f, 0.f, 0.f};
        oa[1] = (f32x4){0.f, 0.f, 0.f, 0.f};
#pragma unroll
        for (int ks = 0; ks < 8; ++ks) {
            int kc = ks * 4 + koct;
            bf16x8 pa = *(const bf16x8*)&pw[r16 * 256 + ((kc ^ (r16 & 7)) << 3)];
#pragma unroll
            for (int n = 0; n < 2; ++n) {
                int row = n * 16 + r16;
                bf16x8 vf = *(const bf16x8*)&vt_sw[row * 256 + ((kc ^ (row & 7)) << 3)];
                oa[n] = __builtin_amdgcn_mfma_f32_16x16x32_bf16(pa, vf, oa[n], 0, 0, 0);
            }
        }
#pragma unroll
        for (int n = 0; n < 2; ++n)
#pragma unroll
            for (int q = 0; q < 4; ++q)
                wvout[((size_t)b * 256 + tb + koct * 4 + q) * 32 + n * 16 + r16] = oa[n][q];
    }
}

// ---------------------------------------------------------------------------
// Kernel 5 (round-13): LN2 + complex linear via MFMA (K=32) + one-pass LN3
// + PReLU + residual.
// ---------------------------------------------------------------------------
__global__ __launch_bounds__(256) void k_post(const float* __restrict__ wv,
                                              const float* __restrict__ in,
                                              const float* __restrict__ g2,
                                              const float* __restrict__ b2,
                                              const float* __restrict__ Wr,
                                              const float* __restrict__ br,
                                              const float* __restrict__ Wi,
                                              const float* __restrict__ bi,
                                              const float* __restrict__ g3,
                                              const float* __restrict__ b3,
                                              const float* __restrict__ pa,
                                              float* __restrict__ outp) {
    __shared__ float xv[32][36];          // 144B row stride
    __shared__ float out_s[64][65];
    const int tid = threadIdx.x;
    const int n = blockIdx.z, f = blockIdx.y, t0 = blockIdx.x * 32;
    const int b = n * 256 + f;
    const int lane = tid & 63, w = tid >> 6;
    const int r16 = lane & 15, koct = lane >> 4;
    const int tt = w & 1, ri = w >> 1;

    for (int idx = tid; idx < 1024; idx += 256) {
        int dt = idx >> 5, j = idx & 31;
        xv[dt][j] = wv[((size_t)b * 256 + t0 + dt) * 32 + j];
    }

    bf16x8 bfr[4];
    float bias_v[4], g3v[4], b3v[4];
    const int kofs = (koct < 2) ? koct * 8 : (koct - 2) * 8;
#pragma unroll
    for (int ct = 0; ct < 4; ++ct) {
        int c = ct * 16 + r16;
        const float* srcW = (ri == 0) ? ((koct < 2) ? Wr : Wi)
                                      : ((koct < 2) ? Wi : Wr);
        float sgn = (ri == 0 && koct >= 2) ? -1.f : 1.f;
        float4 wa = *(const float4*)(srcW + c * 16 + kofs);
        float4 wb = *(const float4*)(srcW + c * 16 + kofs + 4);
        union { ushort u[8]; bf16x8 v; } pk;
        pk.u[0] = f2bf(sgn * wa.x); pk.u[1] = f2bf(sgn * wa.y);
        pk.u[2] = f2bf(sgn * wa.z); pk.u[3] = f2bf(sgn * wa.w);
        pk.u[4] = f2bf(sgn * wb.x); pk.u[5] = f2bf(sgn * wb.y);
        pk.u[6] = f2bf(sgn * wb.z); pk.u[7] = f2bf(sgn * wb.w);
        bfr[ct] = pk.v;
        bias_v[ct] = (ri == 0) ? (br[c] - bi[c]) : (br[c] + bi[c]);
        g3v[ct] = g3[c];
        b3v[ct] = b3[c];
    }
    const float alpha = pa[0];
    __syncthreads();

#pragma unroll 1
    for (int r = 0; r < 4; ++r) {
        int dt = w * 8 + r * 2 + (lane >> 5);
        int j = lane & 31;
        float v = xv[dt][j];
        float mean = hredsum(v) * 0.03125f;
        float d = v - mean;
        float var = hredsum(d * d) * 0.03125f;
        float inv = __builtin_amdgcn_rsqf(var + 1e-5f);
        xv[dt][j] = d * inv * g2[j] + b2[j];
    }
    __syncthreads();

    const float* xrow = &xv[tt * 16 + r16][koct * 8];
    float4 a0 = *(const float4*)xrow;
    float4 a1 = *(const float4*)(xrow + 4);
    uint4 ap;
    __asm__ volatile("v_cvt_pk_bf16_f32 %0, %1, %2" : "=v"(ap.x) : "v"(a0.x), "v"(a0.y));
    __asm__ volatile("v_cvt_pk_bf16_f32 %0, %1, %2" : "=v"(ap.y) : "v"(a0.z), "v"(a0.w));
    __asm__ volatile("v_cvt_pk_bf16_f32 %0, %1, %2" : "=v"(ap.z) : "v"(a1.x), "v"(a1.y));
    __asm__ volatile("v_cvt_pk_bf16_f32 %0, %1, %2" : "=v"(ap.w) : "v"(a1.z), "v"(a1.w));
    bf16x8 af = __builtin_bit_cast(bf16x8, ap);

    f32x4 acc[4];
#pragma unroll
    for (int ct = 0; ct < 4; ++ct) {
        acc[ct] = (f32x4){0.f, 0.f, 0.f, 0.f};
        acc[ct] = __builtin_amdgcn_mfma_f32_16x16x32_bf16(af, bfr[ct], acc[ct], 0, 0, 0);
    }

    float val[4][4];
    float s[4] = {0.f, 0.f, 0.f, 0.f}, sq[4] = {0.f, 0.f, 0.f, 0.f};
#pragma unroll
    for (int ct = 0; ct < 4; ++ct)
#pragma unroll
        for (int q = 0; q < 4; ++q) {
            float v = acc[ct][q] + bias_v[ct];
            val[ct][q] = v;
            s[q] += v;
            sq[q] += v * v;
        }
#pragma unroll
    for (int off = 1; off < 16; off <<= 1)
#pragma unroll
        for (int q = 0; q < 4; ++q) {
            s[q]  += __shfl_xor(s[q], off);
            sq[q] += __shfl_xor(sq[q], off);
        }
#pragma unroll
    for (int q = 0; q < 4; ++q) {
        float m = s[q] * 0.015625f;
        float var = fmaxf(sq[q] * 0.015625f - m * m, 0.f);
        float inv = __builtin_amdgcn_rsqf(var + 1e-5f);
        int t2 = (tt * 16 + koct * 4 + q) * 2 + ri;
#pragma unroll
        for (int ct = 0; ct < 4; ++ct) {
            float nv = (val[ct][q] - m) * inv * g3v[ct] + b3v[ct];
            nv = (nv >= 0.f) ? nv : alpha * nv;
            out_s[ct * 16 + r16][t2] = nv;
        }
    }
    __syncthreads();

    const int cc = tid >> 2, q = tid & 3;
    size_t base = ((size_t)(n * 64 + cc) * 256 + f) * 512 + t0 * 2 + q * 16;
#pragma unroll
    for (int e = 0; e < 4; ++e) {
        float4 iv = *(const float4*)(in + base + e * 4);
        int k0 = q * 16 + e * 4;
        float4 ov;
        ov.x = out_s[cc][k0]     + iv.x;
        ov.y = out_s[cc][k0 + 1] + iv.y;
        ov.z = out_s[cc][k0 + 2] + iv.z;
        ov.w = out_s[cc][k0 + 3] + iv.w;
        *(float4*)(outp + base + e * 4) = ov;
    }
}

// ---------------------------------------------------------------------------
extern "C" void kernel_launch(void* const* d_in, const int* in_sizes, int n_in,
                              void* d_out, int out_size, void* d_ws, size_t ws_size,
                              hipStream_t stream) {
    const float* in   = (const float*)d_in[0];
    const float* g1   = (const float*)d_in[1];
    const float* b1   = (const float*)d_in[2];
    const float* Wq   = (const float*)d_in[3];
    const float* Whq  = (const float*)d_in[4];
    const float* bihq = (const float*)d_in[5];
    const float* bhhq = (const float*)d_in[6];
    const float* Wk   = (const float*)d_in[7];
    const float* Whk  = (const float*)d_in[8];
    const float* bihk = (const float*)d_in[9];
    const float* bhhk = (const float*)d_in[10];
    const float* Wv   = (const float*)d_in[11];
    const float* Whv  = (const float*)d_in[12];
    const float* bihv = (const float*)d_in[13];
    const float* bhhv = (const float*)d_in[14];
    const float* g2   = (const float*)d_in[15];
    const float* b2   = (const float*)d_in[16];
    const float* Wr   = (const float*)d_in[17];
    const float* br   = (const float*)d_in[18];
    const float* Wi   = (const float*)d_in[19];
    const float* bi   = (const float*)d_in[20];
    const float* g3   = (const float*)d_in[21];
    const float* b3   = (const float*)d_in[22];
    const float* pa   = (const float*)d_in[23];
    float* outp = (float*)d_out;

    // workspace layout (bytes):
    // [0, 201326592)            gx  bf16  262144*384*2
    // [201326592, 268435456)    xn  bf16  262144*128*2
    // [268435456, 318767104)    qkv bf16  3*262144*32*2
    // [318767104, 352321536)    wv  fp32  262144*32*4
    ushort* gxb  = (ushort*)d_ws;
    ushort* xnb  = (ushort*)((char*)d_ws + 201326592);
    ushort* qkvb = (ushort*)((char*)d_ws + 268435456);
    float*  wvb  = (float*)((char*)d_ws + 318767104);

    k_prep<<<dim3(8, 256, 4), dim3(256), 0, stream>>>(in, g1, b1, xnb);
    k_gemm<<<dim3(2048), dim3(256), 0, stream>>>(xnb, Wq, Wk, Wv,
                                                 bihq, bhhq, bihk, bhhk, bihv, bhhv, gxb);
    k_lstm<<<dim3(192), dim3(128), 0, stream>>>(gxb, Whq, Whk, Whv, qkvb);
    k_attn<<<dim3(1024), dim3(256), 0, stream>>>(qkvb, wvb);
    k_post<<<dim3(8, 256, 4), dim3(256), 0, stream>>>(wvb, in, g2, b2,
                                                      Wr, br, Wi, bi, g3, b3, pa, outp);
}

// Round 22
// 471.763 us; speedup vs baseline: 1.0250x; 1.0014x over previous
//
#include <hip/hip_runtime.h>
#include <hip/hip_bf16.h>
#include <stddef.h>

// Sizes: N=4, C=64, F=256, T=256, B=N*F=1024, D=128, H=32, 4H=128, NG=384

typedef __bf16 bf16x8 __attribute__((ext_vector_type(8)));
typedef float f32x4 __attribute__((ext_vector_type(4)));

__device__ __forceinline__ ushort f2bf(float x) {   // RTNE
    uint u = __builtin_bit_cast(uint, x);
    uint r = (u + 0x7fffu + ((u >> 16) & 1u)) >> 16;
    return (ushort)r;
}

__device__ __forceinline__ float fsig(float x) {
    return __builtin_amdgcn_rcpf(1.f + __expf(-x));
}
__device__ __forceinline__ float ftanh(float x) {
    return 1.f - 2.f * __builtin_amdgcn_rcpf(__expf(2.f * x) + 1.f);
}
__device__ __forceinline__ float wredsum(float v) {
#pragma unroll
    for (int off = 32; off; off >>= 1) v += __shfl_xor(v, off);
    return v;
}
__device__ __forceinline__ float hredsum(float v) {
#pragma unroll
    for (int off = 16; off; off >>= 1) v += __shfl_xor(v, off);
    return v;
}

// ---------------------------------------------------------------------------
// Kernel 1: inputs [N,C,F,T,2] -> xn [B,T,128] (bf16) with LN1 fused.
// Two-pass LN (round-19 verified numerics, absmax 0.031).
// ---------------------------------------------------------------------------
__global__ __launch_bounds__(256) void k_prep(const float* __restrict__ in,
                                              const float* __restrict__ g1,
                                              const float* __restrict__ b1,
                                              ushort* __restrict__ xn) {
    __shared__ float xl[32][129];
    const int n = blockIdx.z, f = blockIdx.y, t0 = blockIdx.x * 32;
    const int tid = threadIdx.x;
    const int c = tid >> 2, q = tid & 3;
    const float* src = in + ((size_t)(n * 64 + c) * 256 + f) * 512 + t0 * 2 + q * 16;
#pragma unroll
    for (int e = 0; e < 4; ++e) {
        float4 v4 = *(const float4*)(src + e * 4);
        int dt = q * 8 + e * 2;
        xl[dt][c]          = v4.x;
        xl[dt][c + 64]     = v4.y;
        xl[dt + 1][c]      = v4.z;
        xl[dt + 1][c + 64] = v4.w;
    }
    __syncthreads();
    const int lane = tid & 63, w = tid >> 6;
    const int b = n * 256 + f;
#pragma unroll 1
    for (int r = 0; r < 8; ++r) {
        int dt = w * 8 + r;
        float a = xl[dt][lane], bb = xl[dt][lane + 64];
        float s = wredsum(a + bb);
        float mean = s * 0.0078125f;
        float da = a - mean, db = bb - mean;
        float var = wredsum(da * da + db * db) * 0.0078125f;
        float inv = __builtin_amdgcn_rsqf(var + 1e-5f);
        size_t base = ((size_t)b * 256 + (t0 + dt)) * 128;
        xn[base + lane]      = f2bf(da * inv * g1[lane] + b1[lane]);
        xn[base + lane + 64] = f2bf(db * inv * g1[lane + 64] + b1[lane + 64]);
    }
}

// ---------------------------------------------------------------------------
// Kernel 2 (MFMA): gx[M,384](bf16) = xn[M,128](bf16) @ Wcat^T + (bih+bhh)
// One block per 128-row m-tile; loops l=0..2 (A staged once, W restaged).
// Gate storage permuted: s = 4*j + gi (j=g&31, gi=g>>5).
// Epilogue staged in w_lds -> coalesced uint4 stores (round-19).
// ---------------------------------------------------------------------------
__global__ __launch_bounds__(256) void k_gemm(const ushort* __restrict__ xn,
                                              const float* __restrict__ Wq,
                                              const float* __restrict__ Wk,
                                              const float* __restrict__ Wv,
                                              const float* __restrict__ bihq, const float* __restrict__ bhhq,
                                              const float* __restrict__ bihk, const float* __restrict__ bhhk,
                                              const float* __restrict__ bihv, const float* __restrict__ bhhv,
                                              ushort* __restrict__ gx) {
    __shared__ ushort a_lds[128 * 136];
    __shared__ ushort w_lds[128 * 136];
    const int tid = threadIdx.x;
    const int m0 = blockIdx.x * 128;

#pragma unroll
    for (int p = 0; p < 8; ++p) {
        int idx = p * 256 + tid;
        int r = idx >> 4, c = idx & 15;
        *(uint4*)&a_lds[r * 136 + c * 8] =
            *(const uint4*)(xn + (size_t)(m0 + r) * 128 + c * 8);
    }

    const int w = tid >> 6, lane = tid & 63;
    const int wr = w >> 1, wc = w & 1;
    const int row16 = lane & 15, koct = lane >> 4;

#pragma unroll 1
    for (int l = 0; l < 3; ++l) {
        const float* W   = (l == 0) ? Wq   : (l == 1) ? Wk   : Wv;
        const float* bih = (l == 0) ? bihq : (l == 1) ? bihk : bihv;
        const float* bhh = (l == 0) ? bhhq : (l == 1) ? bhhk : bhhv;
        __syncthreads();   // previous-l stores (from w_lds) done; safe to restage
#pragma unroll
        for (int p = 0; p < 8; ++p) {
            int idx = p * 256 + tid;
            int r = idx >> 4, c = idx & 15;
            const float* wp = W + (size_t)r * 128 + c * 8;
            float4 wa = *(const float4*)wp;
            float4 wb = *(const float4*)(wp + 4);
            union { ushort u[8]; uint4 v; } pk;
            pk.u[0] = f2bf(wa.x); pk.u[1] = f2bf(wa.y); pk.u[2] = f2bf(wa.z); pk.u[3] = f2bf(wa.w);
            pk.u[4] = f2bf(wb.x); pk.u[5] = f2bf(wb.y); pk.u[6] = f2bf(wb.z); pk.u[7] = f2bf(wb.w);
            *(uint4*)&w_lds[r * 136 + c * 8] = pk.v;
        }
        __syncthreads();

        f32x4 acc[4][4];
#pragma unroll
        for (int mi = 0; mi < 4; ++mi)
#pragma unroll
            for (int ni = 0; ni < 4; ++ni) acc[mi][ni] = (f32x4){0.f, 0.f, 0.f, 0.f};

#pragma unroll
        for (int ki = 0; ki < 4; ++ki) {
            bf16x8 af[4], bfr[4];
#pragma unroll
            for (int mi = 0; mi < 4; ++mi)
                af[mi] = *(const bf16x8*)&a_lds[(wr * 64 + mi * 16 + row16) * 136 + ki * 32 + koct * 8];
#pragma unroll
            for (int ni = 0; ni < 4; ++ni)
                bfr[ni] = *(const bf16x8*)&w_lds[(wc * 64 + ni * 16 + row16) * 136 + ki * 32 + koct * 8];
#pragma unroll
            for (int mi = 0; mi < 4; ++mi)
#pragma unroll
                for (int ni = 0; ni < 4; ++ni)
                    acc[mi][ni] = __builtin_amdgcn_mfma_f32_16x16x32_bf16(af[mi], bfr[ni], acc[mi][ni], 0, 0, 0);
        }
        __syncthreads();   // all w_lds MFMA reads complete (all waves)

        // epilogue: bias + s-permuted write into w_lds (scalar, <=2-way banks)
#pragma unroll
        for (int ni = 0; ni < 4; ++ni) {
            int g = wc * 64 + ni * 16 + row16;         // gate 0..127
            float bsv = bih[g] + bhh[g];
            int j = g & 31, gi = g >> 5;
            int s = j * 4 + gi;
#pragma unroll
            for (int mi = 0; mi < 4; ++mi)
#pragma unroll
                for (int q = 0; q < 4; ++q) {
                    int ml = wr * 64 + mi * 16 + koct * 4 + q;
                    w_lds[ml * 136 + s] = f2bf(acc[mi][ni][q] + bsv);
                }
        }
        __syncthreads();
        // coalesced store: 128 rows x 128 ushorts -> full 64B lines
#pragma unroll
        for (int p = 0; p < 8; ++p) {
            int idx = p * 256 + tid;
            int r = idx >> 4, cchunk = idx & 15;
            *(uint4*)&gx[(size_t)(m0 + r) * 384 + l * 128 + cchunk * 8] =
                *(const uint4*)&w_lds[r * 136 + cchunk * 8];
        }
    }
}

// ---------------------------------------------------------------------------
// Kernel 3 (MFMA LSTM, 2-wave gate-split — round-13 version, frozen):
// ---------------------------------------------------------------------------
__global__ __launch_bounds__(128, 1) void k_lstm(const ushort* __restrict__ gx,
                                                 const float* __restrict__ Whq,
                                                 const float* __restrict__ Whk,
                                                 const float* __restrict__ Whv,
                                                 ushort* __restrict__ qkv) {
    __shared__ ushort H[2][16][40];   // [parity][b][j], row stride 80B
    const int tid = threadIdx.x;
    const int w = tid >> 6, lane = tid & 63;
    const int r16 = lane & 15, koct = lane >> 4;
    const int l = blockIdx.x >> 6, bgrp = blockIdx.x & 63;
    const int b = bgrp * 16 + r16;
    const float* Wh = (l == 0) ? Whq : (l == 1) ? Whk : Whv;

    bf16x8 wf[4];
#pragma unroll
    for (int gg = 0; gg < 4; ++gg) {
        int g = 4 * w + gg;
        int jA = 8 * (r16 >> 2) + g;
        int giA = r16 & 3;
        const float* wp = Wh + (size_t)(giA * 32 + jA) * 32 + koct * 8;
        float4 wa = *(const float4*)wp;
        float4 wb = *(const float4*)(wp + 4);
        union { ushort u[8]; bf16x8 v; } pk;
        pk.u[0] = f2bf(wa.x); pk.u[1] = f2bf(wa.y); pk.u[2] = f2bf(wa.z); pk.u[3] = f2bf(wa.w);
        pk.u[4] = f2bf(wb.x); pk.u[5] = f2bf(wb.y); pk.u[6] = f2bf(wb.z); pk.u[7] = f2bf(wb.w);
        wf[gg] = pk.v;
    }

    const ushort* gp = gx + (size_t)b * 98304 + l * 128 + koct * 32 + w * 16;
    uint4 pf[4][2];
#pragma unroll
    for (int tt = 0; tt < 4; ++tt) {
        pf[tt][0] = *(const uint4*)(gp + (size_t)tt * 384);
        pf[tt][1] = *(const uint4*)(gp + (size_t)tt * 384 + 8);
    }

    for (int i = tid; i < 320; i += 128) ((uint*)&H[0][0][0])[i] = 0;
    __syncthreads();

    float cst[4] = {0.f, 0.f, 0.f, 0.f};
    ushort* outp = qkv + ((size_t)(l * 1024 + b)) * 8192 + koct * 8 + w * 4;

#pragma unroll 4
    for (int t = 0; t < 256; ++t) {
        const int sl = t & 3;
        const int p = t & 1;
        bf16x8 hf = *(const bf16x8*)&H[p][r16][koct * 8];

        uint u[8];
        u[0] = pf[sl][0].x; u[1] = pf[sl][0].y; u[2] = pf[sl][0].z; u[3] = pf[sl][0].w;
        u[4] = pf[sl][1].x; u[5] = pf[sl][1].y; u[6] = pf[sl][1].z; u[7] = pf[sl][1].w;
        pf[sl][0] = *(const uint4*)(gp + (size_t)(t + 4) * 384);
        pf[sl][1] = *(const uint4*)(gp + (size_t)(t + 4) * 384 + 8);

        f32x4 acc[4];
#pragma unroll
        for (int gg = 0; gg < 4; ++gg)
#pragma unroll
            for (int q = 0; q < 4; ++q) {
                int v = gg * 4 + q;
                uint w32 = u[v >> 1];
                acc[gg][q] = __builtin_bit_cast(float, (v & 1) ? (w32 & 0xffff0000u) : (w32 << 16));
            }
#pragma unroll
        for (int gg = 0; gg < 4; ++gg)
            acc[gg] = __builtin_amdgcn_mfma_f32_16x16x32_bf16(wf[gg], hf, acc[gg], 0, 0, 0);

        float hv[4];
#pragma unroll
        for (int gg = 0; gg < 4; ++gg) {
            float gi = acc[gg][0], gf = acc[gg][1], gg2 = acc[gg][2], go = acc[gg][3];
            float cN = fsig(gf) * cst[gg] + fsig(gi) * ftanh(gg2);
            cst[gg] = cN;
            hv[gg] = fsig(go) * ftanh(cN);
        }
        uint2 hp;
        __asm__ volatile("v_cvt_pk_bf16_f32 %0, %1, %2" : "=v"(hp.x) : "v"(hv[0]), "v"(hv[1]));
        __asm__ volatile("v_cvt_pk_bf16_f32 %0, %1, %2" : "=v"(hp.y) : "v"(hv[2]), "v"(hv[3]));
        *(uint2*)&H[p ^ 1][r16][koct * 8 + w * 4] = hp;
        *(uint2*)(outp + (size_t)t * 32) = hp;
        __syncthreads();
    }
}

// ---------------------------------------------------------------------------
// Kernel 4 (MFMA): attention. 1 block per b, 4 waves x 64 q-rows each.
// ---------------------------------------------------------------------------
__global__ __launch_bounds__(256) void k_attn(const ushort* __restrict__ qkvb,
                                              float* __restrict__ wvout) {
    __shared__ ushort k_sw[256 * 32];      // 16 KiB
    __shared__ ushort vt_sw[32 * 256];     // 16 KiB
    __shared__ ushort p_sw[4][16 * 256];   // 32 KiB (per-wave private)
    const int tid = threadIdx.x, w = tid >> 6, lane = tid & 63;
    const int b = blockIdx.x;
    const ushort* qb = qkvb + (size_t)b * 8192;
    const ushort* kb = qkvb + 8388608 + (size_t)b * 8192;
    const ushort* vb = qkvb + 16777216 + (size_t)b * 8192;
#pragma unroll
    for (int p = 0; p < 4; ++p) {
        int idx = p * 256 + tid;           // 0..1023 chunks of 8 bf16
        int s = idx >> 2, cc = idx & 3;
        uint4 kv = *(const uint4*)(kb + s * 32 + cc * 8);
        int cK = cc ^ ((s >> 1) & 3);
        *(uint4*)&k_sw[s * 32 + cK * 8] = kv;
        uint4 vv = *(const uint4*)(vb + s * 32 + cc * 8);
        union { uint4 v; ushort u[8]; } un; un.v = vv;
#pragma unroll
        for (int e = 0; e < 8; ++e) {
            int row = cc * 8 + e;
            vt_sw[row * 256 + (((s >> 3) ^ (row & 7)) << 3) + (s & 7)] = un.u[e];
        }
    }
    __syncthreads();
    const int r16 = lane & 15, koct = lane >> 4;
    ushort* pw = p_sw[w];
    bf16x8 qf[4];
#pragma unroll
    for (int i = 0; i < 4; ++i) {
        int t = (w * 4 + i) * 16 + r16;
        qf[i] = *(const bf16x8*)(qb + t * 32 + koct * 8);
    }
#pragma unroll 1
    for (int i = 0; i < 4; ++i) {
        const int tb = (w * 4 + i) * 16;
        f32x4 acc[16];
#pragma unroll
        for (int st = 0; st < 16; ++st) acc[st] = (f32x4){0.f, 0.f, 0.f, 0.f};
#pragma unroll
        for (int st = 0; st < 16; ++st) {
            int s = st * 16 + r16;
            int cK = koct ^ ((s >> 1) & 3);
            bf16x8 kf = *(const bf16x8*)&k_sw[s * 32 + cK * 8];
            acc[st] = __builtin_amdgcn_mfma_f32_16x16x32_bf16(qf[i], kf, acc[st], 0, 0, 0);
        }
        float mx[4] = {-1e30f, -1e30f, -1e30f, -1e30f};
#pragma unroll
        for (int st = 0; st < 16; ++st) {
            int s = st * 16 + r16;
#pragma unroll
            for (int q = 0; q < 4; ++q) {
                int t = tb + koct * 4 + q;
                float v = (s <= t) ? acc[st][q] * 0.25f : 0.f;
                acc[st][q] = v;
                mx[q] = fmaxf(mx[q], v);
            }
        }
#pragma unroll
        for (int off = 1; off < 16; off <<= 1)
#pragma unroll
            for (int q = 0; q < 4; ++q) mx[q] = fmaxf(mx[q], __shfl_xor(mx[q], off));
        float sm[4] = {0.f, 0.f, 0.f, 0.f};
#pragma unroll
        for (int st = 0; st < 16; ++st)
#pragma unroll
            for (int q = 0; q < 4; ++q) {
                float p = __expf(acc[st][q] - mx[q]);
                acc[st][q] = p; sm[q] += p;
            }
#pragma unroll
        for (int off = 1; off < 16; off <<= 1)
#pragma unroll
            for (int q = 0; q < 4; ++q) sm[q] += __shfl_xor(sm[q], off);
        float rs[4];
#pragma unroll
        for (int q = 0; q < 4; ++q) rs[q] = __builtin_amdgcn_rcpf(sm[q]);
#pragma unroll
        for (int st = 0; st < 16; ++st) {
            int schunk = st * 2 + (r16 >> 3), sl = r16 & 7;
#pragma unroll
            for (int q = 0; q < 4; ++q) {
                int tl = koct * 4 + q;
                pw[tl * 256 + ((schunk ^ (tl & 7)) << 3) + sl] = f2bf(acc[st][q] * rs[q]);
            }
        }
        __asm__ volatile("s_waitcnt lgkmcnt(0)" ::: "memory");
        f32x4 oa[2];
        oa[0] = (f32x4){0.f, 0.f, 0.f, 0.f};
        oa[1] = (f32x4){0.f, 0.f, 0.f, 0.f};
#pragma unroll
        for (int ks = 0; ks < 8; ++ks) {
            int kc = ks * 4 + koct;
            bf16x8 pa = *(const bf16x8*)&pw[r16 * 256 + ((kc ^ (r16 & 7)) << 3)];
#pragma unroll
            for (int n = 0; n < 2; ++n) {
                int row = n * 16 + r16;
                bf16x8 vf = *(const bf16x8*)&vt_sw[row * 256 + ((kc ^ (row & 7)) << 3)];
                oa[n] = __builtin_amdgcn_mfma_f32_16x16x32_bf16(pa, vf, oa[n], 0, 0, 0);
            }
        }
#pragma unroll
        for (int n = 0; n < 2; ++n)
#pragma unroll
            for (int q = 0; q < 4; ++q)
                wvout[((size_t)b * 256 + tb + koct * 4 + q) * 32 + n * 16 + r16] = oa[n][q];
    }
}

// ---------------------------------------------------------------------------
// Kernel 5 (round-13): LN2 + complex linear via MFMA (K=32) + one-pass LN3
// + PReLU + residual.
// ---------------------------------------------------------------------------
__global__ __launch_bounds__(256) void k_post(const float* __restrict__ wv,
                                              const float* __restrict__ in,
                                              const float* __restrict__ g2,
                                              const float* __restrict__ b2,
                                              const float* __restrict__ Wr,
                                              const float* __restrict__ br,
                                              const float* __restrict__ Wi,
                                              const float* __restrict__ bi,
                                              const float* __restrict__ g3,
                                              const float* __restrict__ b3,
                                              const float* __restrict__ pa,
                                              float* __restrict__ outp) {
    __shared__ float xv[32][36];          // 144B row stride
    __shared__ float out_s[64][65];
    const int tid = threadIdx.x;
    const int n = blockIdx.z, f = blockIdx.y, t0 = blockIdx.x * 32;
    const int b = n * 256 + f;
    const int lane = tid & 63, w = tid >> 6;
    const int r16 = lane & 15, koct = lane >> 4;
    const int tt = w & 1, ri = w >> 1;

    for (int idx = tid; idx < 1024; idx += 256) {
        int dt = idx >> 5, j = idx & 31;
        xv[dt][j] = wv[((size_t)b * 256 + t0 + dt) * 32 + j];
    }

    bf16x8 bfr[4];
    float bias_v[4], g3v[4], b3v[4];
    const int kofs = (koct < 2) ? koct * 8 : (koct - 2) * 8;
#pragma unroll
    for (int ct = 0; ct < 4; ++ct) {
        int c = ct * 16 + r16;
        const float* srcW = (ri == 0) ? ((koct < 2) ? Wr : Wi)
                                      : ((koct < 2) ? Wi : Wr);
        float sgn = (ri == 0 && koct >= 2) ? -1.f : 1.f;
        float4 wa = *(const float4*)(srcW + c * 16 + kofs);
        float4 wb = *(const float4*)(srcW + c * 16 + kofs + 4);
        union { ushort u[8]; bf16x8 v; } pk;
        pk.u[0] = f2bf(sgn * wa.x); pk.u[1] = f2bf(sgn * wa.y);
        pk.u[2] = f2bf(sgn * wa.z); pk.u[3] = f2bf(sgn * wa.w);
        pk.u[4] = f2bf(sgn * wb.x); pk.u[5] = f2bf(sgn * wb.y);
        pk.u[6] = f2bf(sgn * wb.z); pk.u[7] = f2bf(sgn * wb.w);
        bfr[ct] = pk.v;
        bias_v[ct] = (ri == 0) ? (br[c] - bi[c]) : (br[c] + bi[c]);
        g3v[ct] = g3[c];
        b3v[ct] = b3[c];
    }
    const float alpha = pa[0];
    __syncthreads();

#pragma unroll 1
    for (int r = 0; r < 4; ++r) {
        int dt = w * 8 + r * 2 + (lane >> 5);
        int j = lane & 31;
        float v = xv[dt][j];
        float mean = hredsum(v) * 0.03125f;
        float d = v - mean;
        float var = hredsum(d * d) * 0.03125f;
        float inv = __builtin_amdgcn_rsqf(var + 1e-5f);
        xv[dt][j] = d * inv * g2[j] + b2[j];
    }
    __syncthreads();

    const float* xrow = &xv[tt * 16 + r16][koct * 8];
    float4 a0 = *(const float4*)xrow;
    float4 a1 = *(const float4*)(xrow + 4);
    uint4 ap;
    __asm__ volatile("v_cvt_pk_bf16_f32 %0, %1, %2" : "=v"(ap.x) : "v"(a0.x), "v"(a0.y));
    __asm__ volatile("v_cvt_pk_bf16_f32 %0, %1, %2" : "=v"(ap.y) : "v"(a0.z), "v"(a0.w));
    __asm__ volatile("v_cvt_pk_bf16_f32 %0, %1, %2" : "=v"(ap.z) : "v"(a1.x), "v"(a1.y));
    __asm__ volatile("v_cvt_pk_bf16_f32 %0, %1, %2" : "=v"(ap.w) : "v"(a1.z), "v"(a1.w));
    bf16x8 af = __builtin_bit_cast(bf16x8, ap);

    f32x4 acc[4];
#pragma unroll
    for (int ct = 0; ct < 4; ++ct) {
        acc[ct] = (f32x4){0.f, 0.f, 0.f, 0.f};
        acc[ct] = __builtin_amdgcn_mfma_f32_16x16x32_bf16(af, bfr[ct], acc[ct], 0, 0, 0);
    }

    float val[4][4];
    float s[4] = {0.f, 0.f, 0.f, 0.f}, sq[4] = {0.f, 0.f, 0.f, 0.f};
#pragma unroll
    for (int ct = 0; ct < 4; ++ct)
#pragma unroll
        for (int q = 0; q < 4; ++q) {
            float v = acc[ct][q] + bias_v[ct];
            val[ct][q] = v;
            s[q] += v;
            sq[q] += v * v;
        }
#pragma unroll
    for (int off = 1; off < 16; off <<= 1)
#pragma unroll
        for (int q = 0; q < 4; ++q) {
            s[q]  += __shfl_xor(s[q], off);
            sq[q] += __shfl_xor(sq[q], off);
        }
#pragma unroll
    for (int q = 0; q < 4; ++q) {
        float m = s[q] * 0.015625f;
        float var = fmaxf(sq[q] * 0.015625f - m * m, 0.f);
        float inv = __builtin_amdgcn_rsqf(var + 1e-5f);
        int t2 = (tt * 16 + koct * 4 + q) * 2 + ri;
#pragma unroll
        for (int ct = 0; ct < 4; ++ct) {
            float nv = (val[ct][q] - m) * inv * g3v[ct] + b3v[ct];
            nv = (nv >= 0.f) ? nv : alpha * nv;
            out_s[ct * 16 + r16][t2] = nv;
        }
    }
    __syncthreads();

    const int cc = tid >> 2, q = tid & 3;
    size_t base = ((size_t)(n * 64 + cc) * 256 + f) * 512 + t0 * 2 + q * 16;
#pragma unroll
    for (int e = 0; e < 4; ++e) {
        float4 iv = *(const float4*)(in + base + e * 4);
        int k0 = q * 16 + e * 4;
        float4 ov;
        ov.x = out_s[cc][k0]     + iv.x;
        ov.y = out_s[cc][k0 + 1] + iv.y;
        ov.z = out_s[cc][k0 + 2] + iv.z;
        ov.w = out_s[cc][k0 + 3] + iv.w;
        *(float4*)(outp + base + e * 4) = ov;
    }
}

// ---------------------------------------------------------------------------
extern "C" void kernel_launch(void* const* d_in, const int* in_sizes, int n_in,
                              void* d_out, int out_size, void* d_ws, size_t ws_size,
                              hipStream_t stream) {
    const float* in   = (const float*)d_in[0];
    const float* g1   = (const float*)d_in[1];
    const float* b1   = (const float*)d_in[2];
    const float* Wq   = (const float*)d_in[3];
    const float* Whq  = (const float*)d_in[4];
    const float* bihq = (const float*)d_in[5];
    const float* bhhq = (const float*)d_in[6];
    const float* Wk   = (const float*)d_in[7];
    const float* Whk  = (const float*)d_in[8];
    const float* bihk = (const float*)d_in[9];
    const float* bhhk = (const float*)d_in[10];
    const float* Wv   = (const float*)d_in[11];
    const float* Whv  = (const float*)d_in[12];
    const float* bihv = (const float*)d_in[13];
    const float* bhhv = (const float*)d_in[14];
    const float* g2   = (const float*)d_in[15];
    const float* b2   = (const float*)d_in[16];
    const float* Wr   = (const float*)d_in[17];
    const float* br   = (const float*)d_in[18];
    const float* Wi   = (const float*)d_in[19];
    const float* bi   = (const float*)d_in[20];
    const float* g3   = (const float*)d_in[21];
    const float* b3   = (const float*)d_in[22];
    const float* pa   = (const float*)d_in[23];
    float* outp = (float*)d_out;

    // workspace layout (bytes):
    // [0, 201326592)            gx  bf16  262144*384*2
    // [201326592, 268435456)    xn  bf16  262144*128*2
    // [268435456, 318767104)    qkv bf16  3*262144*32*2
    // [318767104, 352321536)    wv  fp32  262144*32*4
    ushort* gxb  = (ushort*)d_ws;
    ushort* xnb  = (ushort*)((char*)d_ws + 201326592);
    ushort* qkvb = (ushort*)((char*)d_ws + 268435456);
    float*  wvb  = (float*)((char*)d_ws + 318767104);

    k_prep<<<dim3(8, 256, 4), dim3(256), 0, stream>>>(in, g1, b1, xnb);
    k_gemm<<<dim3(2048), dim3(256), 0, stream>>>(xnb, Wq, Wk, Wv,
                                                 bihq, bhhq, bihk, bhhk, bihv, bhhv, gxb);
    k_lstm<<<dim3(192), dim3(128), 0, stream>>>(gxb, Whq, Whk, Whv, qkvb);
    k_attn<<<dim3(1024), dim3(256), 0, stream>>>(qkvb, wvb);
    k_post<<<dim3(8, 256, 4), dim3(256), 0, stream>>>(wvb, in, g2, b2,
                                                      Wr, br, Wi, bi, g3, b3, pa, outp);
}